// Round 8
// baseline (26658.282 us; speedup 1.0000x reference)
//
#include <hip/hip_runtime.h>
#include <stdint.h>

// B=64, L=128, H=512, LAB=128. 8192 strictly-sequential LSTM cell steps
// sharing one (h,c) of size 512:
//   gates[s] = pre[s] + W_p @ h[s-64] + W_hh @ h[s-1]
//   pre[s]   = W_ih[:, :2048] @ [x;hi] + b_ih + b_hh     (parallel GEMM)
//
// ws layout (needs 48MB):
//   [0,32MB)  pre32: bf16-pair-packed u32 [8192][1024]  ([s][g*256 + j>>1])
//   [32,48MB) units: u32 [8192][512], unit = (tag16 << 16) | bf16(h[j])
//             tag = step+1 (1..8192); 0xAA poison tag = 0xAAAA never aliases.
//
// R8: actor-count reduction. 32 WGs x 256 thr = 128 waves; wave k of WG w
// owns h-lanes j0=16w+4k .. +3 (16 gate rows, 256 weight fp32/lane in VGPRs,
// asm-pinned, waves_per_eu(1,1)). Barrier-free (R7's LDS+barrier staging
// regressed: FETCH up, tighter spin re-polls). Poll = 4 u64 agent loads/lane
// (whole row); u-part matvec runs between poll issue and first tag check to
// hide the miss window. Publish = 2 adjacent u64 stores from lane 63.

#define HDIM   512
#define NSTEP  8192
#define XDIM   2048
#define IN5H   2560
#define LSEQ   128
#define LAB    128
#define SPIN_LIMIT 65536

typedef float f32x4 __attribute__((ext_vector_type(4)));
typedef short bf16x8 __attribute__((ext_vector_type(8)));

__device__ __forceinline__ unsigned f2bf(float v){
  unsigned u = __float_as_uint(v);
  u += 0x7fffu + ((u >> 16) & 1u);      // RNE; values bounded (no NaN/Inf)
  return u >> 16;
}
__device__ __forceinline__ float bfu(unsigned half16){   // bf16 bits -> f32
  return __uint_as_float(half16 << 16);
}
template<int CTRL>
__device__ __forceinline__ float dpp_add(float x){
  const int yi = __builtin_amdgcn_update_dpp(0, __float_as_int(x), CTRL, 0xF, 0xF, true);
  return x + __int_as_float(yi);
}
// sum of x across 64 lanes, valid in lane 63 (other lanes partial)
__device__ __forceinline__ float wave_reduce63(float x){
  x = dpp_add<0x111>(x);   // row_shr:1
  x = dpp_add<0x112>(x);   // row_shr:2
  x = dpp_add<0x114>(x);   // row_shr:4
  x = dpp_add<0x118>(x);   // row_shr:8  -> lane15+16k = row sum
  x = dpp_add<0x142>(x);   // row_bcast:15
  x = dpp_add<0x143>(x);   // row_bcast:31 -> lane 63 = total
  return x;
}

// ---------------------------------------------------------------- phase 1
// pre[s][r] = sum_k xcat[s][k]*W_ih[r][k] + b_ih[r] + b_hh[r], bf16-packed.
__global__ __launch_bounds__(256) void gemm_pre(
    const float* __restrict__ x, const float* __restrict__ hi,
    const float* __restrict__ Wih, const float* __restrict__ bih,
    const float* __restrict__ bhh, unsigned* __restrict__ pre32)
{
  __shared__ unsigned short As[128][40];   // +8 pad, 16B-aligned b128 reads
  __shared__ unsigned short Bs[128][40];
  const int tid = threadIdx.x;
  const int bm = blockIdx.x, bn = blockIdx.y;
  const int lane = tid & 63, wv = tid >> 6;
  const int wm = wv & 1, wn = wv >> 1;

  const int srow = tid >> 1;              // staging row 0..127
  const int ch   = (tid & 1) * 16;        // col half of the 32-wide K chunk

  const int gr = bm*128 + srow;           // global s row
  const int bb = gr & 63, tt = gr >> 6;   // s = t*64 + b
  const float* ax = x  + (size_t)(bb*LSEQ + tt) * 1024;
  const float* ah = hi + (size_t)(bb*LSEQ + tt) * 1024;
  const int R = bn*128 + srow;            // global gate row
  const float* bw = Wih + (size_t)R * IN5H;

  f32x4 acc[4][4];
  #pragma unroll
  for (int m=0;m<4;++m)
    #pragma unroll
    for (int n=0;n<4;++n) acc[m][n] = (f32x4){0.f,0.f,0.f,0.f};

  for (int kc = 0; kc < XDIM; kc += 32){
    const int c0 = kc + ch;
    const float* ap = (c0 < 1024) ? (ax + c0) : (ah + (c0 - 1024));
    #pragma unroll
    for (int q=0;q<4;++q){
      float4 va = *(const float4*)(ap + 4*q);
      float4 vb = *(const float4*)(bw + c0 + 4*q);
      ushort4 ua; ua.x=f2bf(va.x); ua.y=f2bf(va.y); ua.z=f2bf(va.z); ua.w=f2bf(va.w);
      ushort4 ub; ub.x=f2bf(vb.x); ub.y=f2bf(vb.y); ub.z=f2bf(vb.z); ub.w=f2bf(vb.w);
      *(ushort4*)&As[srow][ch + 4*q] = ua;
      *(ushort4*)&Bs[srow][ch + 4*q] = ub;
    }
    __syncthreads();
    bf16x8 afr[4], bfr[4];
    const int mr = wm*64 + (lane & 15);
    const int nr = wn*64 + (lane & 15);
    const int ko = (lane >> 4) * 8;
    #pragma unroll
    for (int m=0;m<4;++m) afr[m] = *(const bf16x8*)&As[mr + 16*m][ko];
    #pragma unroll
    for (int n=0;n<4;++n) bfr[n] = *(const bf16x8*)&Bs[nr + 16*n][ko];
    #pragma unroll
    for (int m=0;m<4;++m)
      #pragma unroll
      for (int n=0;n<4;++n)
        acc[m][n] = __builtin_amdgcn_mfma_f32_16x16x32_bf16(afr[m], bfr[n], acc[m][n], 0, 0, 0);
    __syncthreads();
  }
  // C/D layout: col = lane&15 (N side), row = (lane>>4)*4+q (M side)
  #pragma unroll
  for (int n=0;n<4;++n){
    const int scol = bn*128 + wn*64 + 16*n + (lane & 15);
    const float bias = bih[scol] + bhh[scol];
    #pragma unroll
    for (int m=0;m<4;++m){
      const int sr0 = bm*128 + wm*64 + 16*m + (lane >> 4)*4;
      #pragma unroll
      for (int q=0;q<4;++q){
        const float v = acc[m][n][q] + bias;
        const float vn = __shfl_xor(v, 1, 64);     // neighbor col (scol^1)
        if (!(lane & 1)){
          const unsigned word = f2bf(v) | (f2bf(vn) << 16);
          pre32[(size_t)(sr0 + q) * 1024 + (scol >> 1)] = word;
        }
      }
    }
  }
}

// ---------------------------------------------------------------- phase 2
// 128 waves (32 WG x 256 thr); wave k of WG w owns h-lanes 16w+4k..+3.
// Lane l holds weight cols {2l+128c, 2l+128c+1 : c=0..3} per (jj,gate) row.
__global__ __launch_bounds__(256)
__attribute__((amdgpu_waves_per_eu(1,1)))
void lstm_seq(
    const float* __restrict__ Wih, const float* __restrict__ Whh,
    const unsigned* __restrict__ pre32, unsigned* __restrict__ units)
{
  const int tid = threadIdx.x;
  const int l = tid & 63;
  const int j0 = blockIdx.x * 16 + (tid >> 6) * 4;   // owns j0..j0+3

  // ---- weights into VGPRs (once): 4 jj x 4 gates x 8 cols, h & u parts ----
  float wh[4][4][8], wu[4][4][8];
  #pragma unroll
  for (int jj=0; jj<4; ++jj)
    #pragma unroll
    for (int g=0; g<4; ++g){
      const float* ph = Whh + (size_t)(g*HDIM + j0 + jj)*HDIM;
      const float* pu = Wih + (size_t)(g*HDIM + j0 + jj)*IN5H + XDIM;
      #pragma unroll
      for (int k=0; k<8; ++k){
        const int col = 2*l + 128*(k>>1) + (k&1);
        wh[jj][g][k] = ph[col]; wu[jj][g][k] = pu[col];
      }
    }
  // Pin: opaque asm def blocks rematerialization/sinking/spilling heuristics.
  #pragma unroll
  for (int jj=0; jj<4; ++jj)
    #pragma unroll
    for (int g=0; g<4; ++g)
      #pragma unroll
      for (int k=0; k<8; ++k){
        asm volatile("" : "+v"(wh[jj][g][k]));
        asm volatile("" : "+v"(wu[jj][g][k]));
      }

  const int ph0 = j0 >> 1;              // pre halfword base (even)
  float pr[4][4];                       // [jj][g]
  #pragma unroll
  for (int g=0; g<4; ++g){
    const unsigned w0 = pre32[(size_t)0*1024 + g*256 + ph0];
    const unsigned w1 = pre32[(size_t)0*1024 + g*256 + ph0 + 1];
    pr[0][g] = bfu(w0 & 0xffffu); pr[1][g] = bfu(w0 >> 16);
    pr[2][g] = bfu(w1 & 0xffffu); pr[3][g] = bfu(w1 >> 16);
  }

  float uvc[8];                         // u for current step (decoded)
  #pragma unroll
  for (int k=0;k<8;++k) uvc[k] = 0.f;

  float cst[4] = {0.f, 0.f, 0.f, 0.f};  // lane63's 4 c-states
  int dead = 0;

  for (int s = 0; s < NSTEP; ++s){
    const bool pf  = (s + 1 < NSTEP);
    const bool upf = (s >= 63) && pf;   // u(s+1) = h[s-63]

    // ---- issue all loads first (share one round-trip window) ----
    unsigned pw0[4], pw1[4];
    if (pf){
      #pragma unroll
      for (int g=0; g<4; ++g){
        pw0[g] = pre32[(size_t)(s+1)*1024 + g*256 + ph0];
        pw1[g] = pre32[(size_t)(s+1)*1024 + g*256 + ph0 + 1];
      }
    }
    unsigned long long un[4];
    if (upf){
      const unsigned long long* up =
          (const unsigned long long*)(units + (size_t)(s-63)*HDIM) + l;
      #pragma unroll
      for (int c=0;c<4;++c)
        un[c] = __hip_atomic_load(up + 64*c, __ATOMIC_RELAXED, __HIP_MEMORY_SCOPE_AGENT);
    }
    unsigned long long v[4];
    if (s > 0){
      const unsigned long long* hp =
          (const unsigned long long*)(units + (size_t)(s-1)*HDIM) + l;
      #pragma unroll
      for (int c=0;c<4;++c)
        v[c] = __hip_atomic_load(hp + 64*c, __ATOMIC_RELAXED, __HIP_MEMORY_SCOPE_AGENT);
    }

    // ---- u-part matvec while the poll loads are in flight ----
    float acc[4][4];
    #pragma unroll
    for (int jj=0; jj<4; ++jj)
      #pragma unroll
      for (int g=0; g<4; ++g){
        float a = 0.f;
        #pragma unroll
        for (int k=0;k<8;++k) a += wu[jj][g][k]*uvc[k];
        acc[jj][g] = a;
      }

    // ---- spin on h[s-1] tags (first check lands after the u-matvec) ----
    float hv[8];
    if (s == 0){
      #pragma unroll
      for (int k=0;k<8;++k) hv[k] = 0.f;
    } else {
      if (!dead){
        int lok = 1;
        #pragma unroll
        for (int c=0;c<4;++c){
          lok &= (((unsigned)(v[c] >> 16) & 0xffffu) == (unsigned)s);
          lok &= (((unsigned)(v[c] >> 48)) == (unsigned)s);
        }
        int ok = __all(lok), trips = 0;
        while (!ok && ++trips < SPIN_LIMIT){
          const unsigned long long* hp =
              (const unsigned long long*)(units + (size_t)(s-1)*HDIM) + l;
          #pragma unroll
          for (int c=0;c<4;++c)
            v[c] = __hip_atomic_load(hp + 64*c, __ATOMIC_RELAXED, __HIP_MEMORY_SCOPE_AGENT);
          int lk = 1;
          #pragma unroll
          for (int c=0;c<4;++c){
            lk &= (((unsigned)(v[c] >> 16) & 0xffffu) == (unsigned)s);
            lk &= (((unsigned)(v[c] >> 48)) == (unsigned)s);
          }
          ok = __all(lk);
        }
        if (!ok) dead = 1;
      }
      #pragma unroll
      for (int c=0;c<4;++c){
        hv[2*c]   = bfu((unsigned)v[c] & 0xffffu);
        hv[2*c+1] = bfu((unsigned)(v[c] >> 32) & 0xffffu);
      }
    }

    // ---- h-part matvec + reduce (16 independent DPP chains) ----
    #pragma unroll
    for (int jj=0; jj<4; ++jj)
      #pragma unroll
      for (int g=0; g<4; ++g){
        float a = acc[jj][g];
        #pragma unroll
        for (int k=0;k<8;++k) a += wh[jj][g][k]*hv[k];
        acc[jj][g] = wave_reduce63(a);
      }

    // ---- pointwise x4 (only lane 63's chains are valid; it publishes) ----
    unsigned unitv[4];
    #pragma unroll
    for (int jj=0; jj<4; ++jj){
      float gi = acc[jj][0] + pr[jj][0];
      float gf = acc[jj][1] + pr[jj][1];
      float gg = acc[jj][2] + pr[jj][2];
      float go = acc[jj][3] + pr[jj][3];
      gi = 1.f/(1.f + __expf(-gi));
      gf = 1.f/(1.f + __expf(-gf));
      go = 1.f/(1.f + __expf(-go));
      float e2 = __expf(2.f * fminf(fmaxf(gg, -15.f), 15.f));
      gg = (e2 - 1.f) / (e2 + 1.f);
      cst[jj] = gf*cst[jj] + gi*gg;
      float e2c = __expf(2.f * fminf(fmaxf(cst[jj], -15.f), 15.f));
      const float hval = go * ((e2c - 1.f) / (e2c + 1.f));
      unitv[jj] = ((unsigned)(s + 1) << 16) | f2bf(hval);
    }
    if (l == 63){
      unsigned long long* dst =
          (unsigned long long*)(units + (size_t)s*HDIM + j0);
      const unsigned long long d0 =
          (unsigned long long)unitv[0] | ((unsigned long long)unitv[1] << 32);
      const unsigned long long d1 =
          (unsigned long long)unitv[2] | ((unsigned long long)unitv[3] << 32);
      __hip_atomic_store(dst,     d0, __ATOMIC_RELAXED, __HIP_MEMORY_SCOPE_AGENT);
      __hip_atomic_store(dst + 1, d1, __ATOMIC_RELAXED, __HIP_MEMORY_SCOPE_AGENT);
    }

    // ---- finalize prefetches (off critical path) ----
    if (upf){
      int lok = 1;
      #pragma unroll
      for (int c=0;c<4;++c){
        lok &= (((unsigned)(un[c] >> 16) & 0xffffu) == (unsigned)(s-62));
        lok &= (((unsigned)(un[c] >> 48)) == (unsigned)(s-62));
      }
      if (!__all(lok) && !dead){
        // should never happen (62-step slack); bounded fallback spin
        const unsigned long long* up =
            (const unsigned long long*)(units + (size_t)(s-63)*HDIM) + l;
        int trips = 0, ok;
        do {
          #pragma unroll
          for (int c=0;c<4;++c)
            un[c] = __hip_atomic_load(up + 64*c, __ATOMIC_RELAXED, __HIP_MEMORY_SCOPE_AGENT);
          int lk = 1;
          #pragma unroll
          for (int c=0;c<4;++c){
            lk &= (((unsigned)(un[c] >> 16) & 0xffffu) == (unsigned)(s-62));
            lk &= (((unsigned)(un[c] >> 48)) == (unsigned)(s-62));
          }
          ok = __all(lk);
        } while (!ok && ++trips < SPIN_LIMIT);
        if (!ok) dead = 1;
      }
      #pragma unroll
      for (int c=0;c<4;++c){
        uvc[2*c]   = bfu((unsigned)un[c] & 0xffffu);
        uvc[2*c+1] = bfu((unsigned)(un[c] >> 32) & 0xffffu);
      }
    } else {
      #pragma unroll
      for (int k=0;k<8;++k) uvc[k] = 0.f;
    }
    if (pf){
      #pragma unroll
      for (int g=0; g<4; ++g){
        pr[0][g] = bfu(pw0[g] & 0xffffu); pr[1][g] = bfu(pw0[g] >> 16);
        pr[2][g] = bfu(pw1[g] & 0xffffu); pr[3][g] = bfu(pw1[g] >> 16);
      }
    }
  }
}

// ---------------------------------------------------------------- phase 3
// y[b][t][lab] = sum_j h[s][j] * W_fc[lab][j] + b_fc[lab],  s = t*64 + b
__global__ __launch_bounds__(256) void fc_kernel(
    const unsigned* __restrict__ units,
    const float* __restrict__ Wfc, const float* __restrict__ bfc,
    float* __restrict__ out)
{
  __shared__ float hbuf[8][512];
  const int tid = threadIdx.x;
  const int s0 = blockIdx.x * 8;
  #pragma unroll
  for (int r=0;r<16;++r){
    const int q = tid + 256*r;                 // 0..4095
    const int si = q >> 9, j = q & 511;
    hbuf[si][j] = bfu(units[(size_t)(s0 + si)*HDIM + j] & 0xffffu);
  }
  __syncthreads();
  const int lab = tid & 127, sg = tid >> 7;
  const float* wrow = Wfc + (size_t)lab * HDIM;
  const float bias = bfc[lab];
  for (int si = sg; si < 8; si += 2){
    float sum = 0.f;
    #pragma unroll 4
    for (int j=0;j<HDIM;j+=4){
      const float4 wv = *(const float4*)(wrow + j);
      sum += wv.x*hbuf[si][j] + wv.y*hbuf[si][j+1]
           + wv.z*hbuf[si][j+2] + wv.w*hbuf[si][j+3];
    }
    const int s = s0 + si;
    const int bb = s & 63, tt = s >> 6;
    out[((size_t)(bb*LSEQ + tt))*LAB + lab] = sum + bias;
  }
}

__global__ void sentinel_kernel(float* out, int n){
  const int i = blockIdx.x*256 + threadIdx.x;
  if (i < n) out[i] = 12345.0f;     // diagnostic: ws_size too small
}

extern "C" void kernel_launch(void* const* d_in, const int* in_sizes, int n_in,
                              void* d_out, int out_size, void* d_ws, size_t ws_size,
                              hipStream_t stream)
{
  const float* x   = (const float*)d_in[0];
  const float* hi  = (const float*)d_in[1];
  const float* Wih = (const float*)d_in[2];
  const float* Whh = (const float*)d_in[3];
  const float* bih = (const float*)d_in[4];
  const float* bhh = (const float*)d_in[5];
  const float* Wfc = (const float*)d_in[6];
  const float* bfc = (const float*)d_in[7];
  float* out = (float*)d_out;

  const size_t MB = 1024*1024;
  if (ws_size >= 48*MB){
    unsigned* pre32 = (unsigned*)d_ws;                          // 32MB
    unsigned* units = (unsigned*)((char*)d_ws + 32*MB);         // 16MB
    gemm_pre<<<dim3(64, 16), 256, 0, stream>>>(x, hi, Wih, bih, bhh, pre32);
    lstm_seq<<<32, 256, 0, stream>>>(Wih, Whh, pre32, units);
    fc_kernel<<<1024, 256, 0, stream>>>(units, Wfc, bfc, out);
  } else {
    sentinel_kernel<<<(out_size + 255)/256, 256, 0, stream>>>(out, out_size);
  }
}

// Round 9
// 15313.603 us; speedup vs baseline: 1.7408x; 1.7408x over previous
//
#include <hip/hip_runtime.h>
#include <stdint.h>

// B=64, L=128, H=512, LAB=128. 8192 strictly-sequential LSTM cell steps
// sharing one (h,c) of size 512:
//   gates[s] = pre[s] + W_p @ h[s-64] + W_hh @ h[s-1]
//   pre[s]   = W_ih[:, :2048] @ [x;hi] + b_ih + b_hh     (parallel GEMM)
//
// ws layout (needs 48MB):
//   [0,32MB)  pre32: bf16-pair-packed u32 [8192][1024]  ([s][g*256 + j>>1])
//   [32,48MB) units: u32 [8192][512], unit = (tag16 << 16) | bf16(h[j])
//             tag = step+1 (1..8192); 0xAA poison tag = 0xAAAA never aliases.
//
// lstm_seq = R6 structure (512 waves, 128 WG x 256 thr, wave j0 owns h-lane
// j0, weights asm-pinned in VGPRs, waves_per_eu(1,1)) + R9 issue-order fix:
// vmcnt retires in ISSUE order, so R6's order (pre, u, h) forced the first
// h-tag check to drain the HBM-latency pre/u loads (vmcnt(0)). Now h loads
// issue FIRST (check = vmcnt(8)); pre/u prefetches fly across the spin;
// pre prefetch distance = 2 steps; u-part matvec fills the wait window.

#define HDIM   512
#define NSTEP  8192
#define XDIM   2048
#define IN5H   2560
#define LSEQ   128
#define LAB    128
#define SPIN_LIMIT 65536

typedef float f32x4 __attribute__((ext_vector_type(4)));
typedef short bf16x8 __attribute__((ext_vector_type(8)));

__device__ __forceinline__ unsigned f2bf(float v){
  unsigned u = __float_as_uint(v);
  u += 0x7fffu + ((u >> 16) & 1u);      // RNE; values bounded (no NaN/Inf)
  return u >> 16;
}
__device__ __forceinline__ float bfu(unsigned half16){   // bf16 bits -> f32
  return __uint_as_float(half16 << 16);
}
template<int CTRL>
__device__ __forceinline__ float dpp_add(float x){
  const int yi = __builtin_amdgcn_update_dpp(0, __float_as_int(x), CTRL, 0xF, 0xF, true);
  return x + __int_as_float(yi);
}
// sum of x across 64 lanes, valid in lane 63 (other lanes partial)
__device__ __forceinline__ float wave_reduce63(float x){
  x = dpp_add<0x111>(x);   // row_shr:1
  x = dpp_add<0x112>(x);   // row_shr:2
  x = dpp_add<0x114>(x);   // row_shr:4
  x = dpp_add<0x118>(x);   // row_shr:8  -> lane15+16k = row sum
  x = dpp_add<0x142>(x);   // row_bcast:15
  x = dpp_add<0x143>(x);   // row_bcast:31 -> lane 63 = total
  return x;
}

// ---------------------------------------------------------------- phase 1
// pre[s][r] = sum_k xcat[s][k]*W_ih[r][k] + b_ih[r] + b_hh[r], bf16-packed.
__global__ __launch_bounds__(256) void gemm_pre(
    const float* __restrict__ x, const float* __restrict__ hi,
    const float* __restrict__ Wih, const float* __restrict__ bih,
    const float* __restrict__ bhh, unsigned* __restrict__ pre32)
{
  __shared__ unsigned short As[128][40];   // +8 pad, 16B-aligned b128 reads
  __shared__ unsigned short Bs[128][40];
  const int tid = threadIdx.x;
  const int bm = blockIdx.x, bn = blockIdx.y;
  const int lane = tid & 63, wv = tid >> 6;
  const int wm = wv & 1, wn = wv >> 1;

  const int srow = tid >> 1;              // staging row 0..127
  const int ch   = (tid & 1) * 16;        // col half of the 32-wide K chunk

  const int gr = bm*128 + srow;           // global s row
  const int bb = gr & 63, tt = gr >> 6;   // s = t*64 + b
  const float* ax = x  + (size_t)(bb*LSEQ + tt) * 1024;
  const float* ah = hi + (size_t)(bb*LSEQ + tt) * 1024;
  const int R = bn*128 + srow;            // global gate row
  const float* bw = Wih + (size_t)R * IN5H;

  f32x4 acc[4][4];
  #pragma unroll
  for (int m=0;m<4;++m)
    #pragma unroll
    for (int n=0;n<4;++n) acc[m][n] = (f32x4){0.f,0.f,0.f,0.f};

  for (int kc = 0; kc < XDIM; kc += 32){
    const int c0 = kc + ch;
    const float* ap = (c0 < 1024) ? (ax + c0) : (ah + (c0 - 1024));
    #pragma unroll
    for (int q=0;q<4;++q){
      float4 va = *(const float4*)(ap + 4*q);
      float4 vb = *(const float4*)(bw + c0 + 4*q);
      ushort4 ua; ua.x=f2bf(va.x); ua.y=f2bf(va.y); ua.z=f2bf(va.z); ua.w=f2bf(va.w);
      ushort4 ub; ub.x=f2bf(vb.x); ub.y=f2bf(vb.y); ub.z=f2bf(vb.z); ub.w=f2bf(vb.w);
      *(ushort4*)&As[srow][ch + 4*q] = ua;
      *(ushort4*)&Bs[srow][ch + 4*q] = ub;
    }
    __syncthreads();
    bf16x8 afr[4], bfr[4];
    const int mr = wm*64 + (lane & 15);
    const int nr = wn*64 + (lane & 15);
    const int ko = (lane >> 4) * 8;
    #pragma unroll
    for (int m=0;m<4;++m) afr[m] = *(const bf16x8*)&As[mr + 16*m][ko];
    #pragma unroll
    for (int n=0;n<4;++n) bfr[n] = *(const bf16x8*)&Bs[nr + 16*n][ko];
    #pragma unroll
    for (int m=0;m<4;++m)
      #pragma unroll
      for (int n=0;n<4;++n)
        acc[m][n] = __builtin_amdgcn_mfma_f32_16x16x32_bf16(afr[m], bfr[n], acc[m][n], 0, 0, 0);
    __syncthreads();
  }
  // C/D layout: col = lane&15 (N side), row = (lane>>4)*4+q (M side)
  #pragma unroll
  for (int n=0;n<4;++n){
    const int scol = bn*128 + wn*64 + 16*n + (lane & 15);
    const float bias = bih[scol] + bhh[scol];
    #pragma unroll
    for (int m=0;m<4;++m){
      const int sr0 = bm*128 + wm*64 + 16*m + (lane >> 4)*4;
      #pragma unroll
      for (int q=0;q<4;++q){
        const float v = acc[m][n][q] + bias;
        const float vn = __shfl_xor(v, 1, 64);     // neighbor col (scol^1)
        if (!(lane & 1)){
          const unsigned word = f2bf(v) | (f2bf(vn) << 16);
          pre32[(size_t)(sr0 + q) * 1024 + (scol >> 1)] = word;
        }
      }
    }
  }
}

// ---------------------------------------------------------------- phase 2
// 512 independent waves; wave j0 owns h-lane j0 (gate rows {g*512+j0}).
// Lane l holds weight cols {2l+128c, 2l+128c+1 : c=0..3} (u64-load layout).
__global__ __launch_bounds__(256)
__attribute__((amdgpu_waves_per_eu(1,1)))
void lstm_seq(
    const float* __restrict__ Wih, const float* __restrict__ Whh,
    const unsigned* __restrict__ pre32, unsigned* __restrict__ units)
{
  const int tid = threadIdx.x;
  const int l = tid & 63;
  const int j0 = blockIdx.x * 4 + (tid >> 6);      // 0..511

  // ---- weights into VGPRs (once): col(k) = 2l + 128*(k>>1) + (k&1) ----
  float wh[4][8], wu[4][8];
  #pragma unroll
  for (int g=0; g<4; ++g){
    const float* ph = Whh + (size_t)(g*HDIM + j0)*HDIM;
    const float* pu = Wih + (size_t)(g*HDIM + j0)*IN5H + XDIM;
    #pragma unroll
    for (int k=0; k<8; ++k){
      const int col = 2*l + 128*(k>>1) + (k&1);
      wh[g][k] = ph[col]; wu[g][k] = pu[col];
    }
  }
  // Pin: opaque asm def blocks rematerialization/sinking of the loads.
  #pragma unroll
  for (int g=0; g<4; ++g)
    #pragma unroll
    for (int k=0; k<8; ++k){
      asm volatile("" : "+v"(wh[g][k]));
      asm volatile("" : "+v"(wu[g][k]));
    }

  const int phalf = j0 >> 1, psel = j0 & 1;
  // pre pipeline: pr = pre[s], prn = pre[s+1]; loads issued for pre[s+2].
  float pr[4], prn[4];
  #pragma unroll
  for (int g=0; g<4; ++g){
    const unsigned w0 = pre32[(size_t)0*1024 + g*256 + phalf];
    pr[g] = psel ? bfu(w0 >> 16) : bfu(w0 & 0xffffu);
    const unsigned w1 = pre32[(size_t)1*1024 + g*256 + phalf];
    prn[g] = psel ? bfu(w1 >> 16) : bfu(w1 & 0xffffu);
  }

  float uvc[8];                       // u for current step (decoded)
  #pragma unroll
  for (int k=0;k<8;++k) uvc[k] = 0.f;

  float cst = 0.f;
  int dead = 0;

  for (int s = 0; s < NSTEP; ++s){
    // ---- 1. h[s-1] poll loads issue FIRST (oldest in vmcnt order) ----
    unsigned long long v[4];
    const unsigned long long* hp =
        (const unsigned long long*)(units + (size_t)(s-1)*HDIM) + l;
    if (s > 0){
      #pragma unroll
      for (int c=0;c<4;++c)
        v[c] = __hip_atomic_load(hp + 64*c, __ATOMIC_RELAXED, __HIP_MEMORY_SCOPE_AGENT);
    }
    // VMEM may not cross (ALU may): pins h loads before the prefetches, so
    // the h tag check waits only on its own 4 loads, not the HBM prefetches.
    __builtin_amdgcn_sched_barrier(0x1);

    // ---- 2. prefetch issues: pre[s+2] and u(s+1) = h[s-63] ----
    const bool pf2 = (s + 2 < NSTEP);
    const bool upf = (s >= 63) && (s + 1 < NSTEP);
    unsigned pw[4];
    if (pf2){
      #pragma unroll
      for (int g=0; g<4; ++g)
        pw[g] = pre32[(size_t)(s+2)*1024 + g*256 + phalf];
    }
    unsigned long long un[4];
    if (upf){
      const unsigned long long* up =
          (const unsigned long long*)(units + (size_t)(s-63)*HDIM) + l;
      #pragma unroll
      for (int c=0;c<4;++c)
        un[c] = __hip_atomic_load(up + 64*c, __ATOMIC_RELAXED, __HIP_MEMORY_SCOPE_AGENT);
    }
    __builtin_amdgcn_sched_barrier(0x1);

    // ---- 3. u-part matvec while loads fly (uvc = u for step s) ----
    float a0=0.f, a1=0.f, a2=0.f, a3=0.f;
    #pragma unroll
    for (int k=0;k<8;++k){
      a0 += wu[0][k]*uvc[k]; a1 += wu[1][k]*uvc[k];
      a2 += wu[2][k]*uvc[k]; a3 += wu[3][k]*uvc[k];
    }

    // ---- 4. spin on h[s-1] tags (check needs only the 4 h loads) ----
    float hv[8];
    if (s == 0){
      #pragma unroll
      for (int k=0;k<8;++k) hv[k] = 0.f;
    } else {
      if (!dead){
        int lok = 1;
        #pragma unroll
        for (int c=0;c<4;++c){
          lok &= (((unsigned)(v[c] >> 16) & 0xffffu) == (unsigned)s);
          lok &= (((unsigned)(v[c] >> 48)) == (unsigned)s);
        }
        int ok = __all(lok), trips = 0;
        while (!ok && ++trips < SPIN_LIMIT){
          #pragma unroll
          for (int c=0;c<4;++c)
            v[c] = __hip_atomic_load(hp + 64*c, __ATOMIC_RELAXED, __HIP_MEMORY_SCOPE_AGENT);
          int lk = 1;
          #pragma unroll
          for (int c=0;c<4;++c){
            lk &= (((unsigned)(v[c] >> 16) & 0xffffu) == (unsigned)s);
            lk &= (((unsigned)(v[c] >> 48)) == (unsigned)s);
          }
          ok = __all(lk);
        }
        if (!ok) dead = 1;
      }
      #pragma unroll
      for (int c=0;c<4;++c){
        hv[2*c]   = bfu((unsigned)v[c] & 0xffffu);
        hv[2*c+1] = bfu((unsigned)(v[c] >> 32) & 0xffffu);
      }
    }

    // ---- 5. h-part matvec + reduce ----
    #pragma unroll
    for (int k=0;k<8;++k){
      a0 += wh[0][k]*hv[k]; a1 += wh[1][k]*hv[k];
      a2 += wh[2][k]*hv[k]; a3 += wh[3][k]*hv[k];
    }
    a0 = wave_reduce63(a0);
    a1 = wave_reduce63(a1);
    a2 = wave_reduce63(a2);
    a3 = wave_reduce63(a3);

    // ---- pointwise (only lane 63's chain is valid; only it publishes) ----
    float gi = a0 + pr[0];
    float gf = a1 + pr[1];
    float gg = a2 + pr[2];
    float go = a3 + pr[3];
    gi = 1.f/(1.f + __expf(-gi));
    gf = 1.f/(1.f + __expf(-gf));
    go = 1.f/(1.f + __expf(-go));
    float e2 = __expf(2.f * fminf(fmaxf(gg, -15.f), 15.f));
    gg = (e2 - 1.f) / (e2 + 1.f);
    cst = gf*cst + gi*gg;
    float e2c = __expf(2.f * fminf(fmaxf(cst, -15.f), 15.f));
    const float hval = go * ((e2c - 1.f) / (e2c + 1.f));

    if (l == 63){
      const unsigned unit = ((unsigned)(s + 1) << 16) | f2bf(hval);
      __hip_atomic_store(units + (size_t)s*HDIM + j0, unit,
                         __ATOMIC_RELAXED, __HIP_MEMORY_SCOPE_AGENT);
    }

    // ---- 6. finalize u prefetch (off critical path; tag s-62) ----
    if (upf){
      int lok = 1;
      #pragma unroll
      for (int c=0;c<4;++c){
        lok &= (((unsigned)(un[c] >> 16) & 0xffffu) == (unsigned)(s-62));
        lok &= (((unsigned)(un[c] >> 48)) == (unsigned)(s-62));
      }
      if (!__all(lok) && !dead){
        // should never happen (62-step slack); bounded fallback spin
        const unsigned long long* up =
            (const unsigned long long*)(units + (size_t)(s-63)*HDIM) + l;
        int trips = 0, ok;
        do {
          #pragma unroll
          for (int c=0;c<4;++c)
            un[c] = __hip_atomic_load(up + 64*c, __ATOMIC_RELAXED, __HIP_MEMORY_SCOPE_AGENT);
          int lk = 1;
          #pragma unroll
          for (int c=0;c<4;++c){
            lk &= (((unsigned)(un[c] >> 16) & 0xffffu) == (unsigned)(s-62));
            lk &= (((unsigned)(un[c] >> 48)) == (unsigned)(s-62));
          }
          ok = __all(lk);
        } while (!ok && ++trips < SPIN_LIMIT);
        if (!ok) dead = 1;
      }
      #pragma unroll
      for (int c=0;c<4;++c){
        uvc[2*c]   = bfu((unsigned)un[c] & 0xffffu);
        uvc[2*c+1] = bfu((unsigned)(un[c] >> 32) & 0xffffu);
      }
    } else {
      #pragma unroll
      for (int k=0;k<8;++k) uvc[k] = 0.f;
    }

    // ---- 7. rotate pre pipeline: pr <- prn <- decode(pw for s+2) ----
    #pragma unroll
    for (int g=0; g<4; ++g) pr[g] = prn[g];
    if (pf2){
      #pragma unroll
      for (int g=0; g<4; ++g)
        prn[g] = psel ? bfu(pw[g] >> 16) : bfu(pw[g] & 0xffffu);
    }
  }
}

// ---------------------------------------------------------------- phase 3
// y[b][t][lab] = sum_j h[s][j] * W_fc[lab][j] + b_fc[lab],  s = t*64 + b
__global__ __launch_bounds__(256) void fc_kernel(
    const unsigned* __restrict__ units,
    const float* __restrict__ Wfc, const float* __restrict__ bfc,
    float* __restrict__ out)
{
  __shared__ float hbuf[8][512];
  const int tid = threadIdx.x;
  const int s0 = blockIdx.x * 8;
  #pragma unroll
  for (int r=0;r<16;++r){
    const int q = tid + 256*r;                 // 0..4095
    const int si = q >> 9, j = q & 511;
    hbuf[si][j] = bfu(units[(size_t)(s0 + si)*HDIM + j] & 0xffffu);
  }
  __syncthreads();
  const int lab = tid & 127, sg = tid >> 7;
  const float* wrow = Wfc + (size_t)lab * HDIM;
  const float bias = bfc[lab];
  for (int si = sg; si < 8; si += 2){
    float sum = 0.f;
    #pragma unroll 4
    for (int j=0;j<HDIM;j+=4){
      const float4 wv = *(const float4*)(wrow + j);
      sum += wv.x*hbuf[si][j] + wv.y*hbuf[si][j+1]
           + wv.z*hbuf[si][j+2] + wv.w*hbuf[si][j+3];
    }
    const int s = s0 + si;
    const int bb = s & 63, tt = s >> 6;
    out[((size_t)(bb*LSEQ + tt))*LAB + lab] = sum + bias;
  }
}

__global__ void sentinel_kernel(float* out, int n){
  const int i = blockIdx.x*256 + threadIdx.x;
  if (i < n) out[i] = 12345.0f;     // diagnostic: ws_size too small
}

extern "C" void kernel_launch(void* const* d_in, const int* in_sizes, int n_in,
                              void* d_out, int out_size, void* d_ws, size_t ws_size,
                              hipStream_t stream)
{
  const float* x   = (const float*)d_in[0];
  const float* hi  = (const float*)d_in[1];
  const float* Wih = (const float*)d_in[2];
  const float* Whh = (const float*)d_in[3];
  const float* bih = (const float*)d_in[4];
  const float* bhh = (const float*)d_in[5];
  const float* Wfc = (const float*)d_in[6];
  const float* bfc = (const float*)d_in[7];
  float* out = (float*)d_out;

  const size_t MB = 1024*1024;
  if (ws_size >= 48*MB){
    unsigned* pre32 = (unsigned*)d_ws;                          // 32MB
    unsigned* units = (unsigned*)((char*)d_ws + 32*MB);         // 16MB
    gemm_pre<<<dim3(64, 16), 256, 0, stream>>>(x, hi, Wih, bih, bhh, pre32);
    lstm_seq<<<128, 256, 0, stream>>>(Wih, Whh, pre32, units);
    fc_kernel<<<1024, 256, 0, stream>>>(units, Wfc, bfc, out);
  } else {
    sentinel_kernel<<<(out_size + 255)/256, 256, 0, stream>>>(out, out_size);
  }
}